// Round 1
// baseline (309.202 us; speedup 1.0000x reference)
//
#include <hip/hip_runtime.h>

#define THREADS 256

__device__ __forceinline__ float dot4f(float4 a, float4 b) {
  return a.x*b.x + a.y*b.y + a.z*b.z + a.w*b.w;
}

// One block = one sample. x_i: [28][28], W: [512][28], b: [512]
// H = sigmoid(x W^T + b) : [28][512]
// G = H H^T : [28][28];  Y = G^{-1} x ;  B = H^T Y : [512][28];  X = G Y : [28][28]
__global__ __launch_bounds__(THREADS, 2) void elm_kernel(
    const float* __restrict__ x, const float* __restrict__ W,
    const float* __restrict__ bias, float* __restrict__ Xout,
    float* __restrict__ Bout)
{
  // Hs[r][h] stored at Hs[r*512 + (h ^ (((r>>1)&7)<<2))]  (bank swizzle)
  __shared__ float Hs[28*512];
  // phase 1: xs[r][c] at r*36+c ; after solve: Yt[c][a] at c*36+a (alias)
  __shared__ float xsb[28*36];
  __shared__ float Gc[28*32];   // G[a][c] at a*32+c

  const int tid = threadIdx.x;
  const int n   = blockIdx.x;
  const float* xi = x + (size_t)n * 784;

  // ---- load x_i into LDS ----
  for (int idx = tid; idx < 784; idx += THREADS) {
    const int r = idx / 28, c = idx - r*28;
    xsb[r*36 + c] = xi[idx];
  }
  __syncthreads();

  // ---- H = sigmoid(x W^T + b), column-swizzled store ----
  {
    const int h0 = tid, h1 = tid + THREADS;
    float w0[28], w1[28];
    const float4* W4 = reinterpret_cast<const float4*>(W);
#pragma unroll
    for (int j4 = 0; j4 < 7; ++j4) {
      const float4 v0 = W4[h0*7 + j4];
      const float4 v1 = W4[h1*7 + j4];
      w0[4*j4+0]=v0.x; w0[4*j4+1]=v0.y; w0[4*j4+2]=v0.z; w0[4*j4+3]=v0.w;
      w1[4*j4+0]=v1.x; w1[4*j4+1]=v1.y; w1[4*j4+2]=v1.z; w1[4*j4+3]=v1.w;
    }
    const float b0 = bias[h0], b1 = bias[h1];
    for (int r = 0; r < 28; ++r) {
      const float4* xr4 = reinterpret_cast<const float4*>(&xsb[r*36]);
      float a0 = b0, a1 = b1;
#pragma unroll
      for (int j4 = 0; j4 < 7; ++j4) {
        const float4 xv = xr4[j4];
        a0 += xv.x*w0[4*j4] + xv.y*w0[4*j4+1] + xv.z*w0[4*j4+2] + xv.w*w0[4*j4+3];
        a1 += xv.x*w1[4*j4] + xv.y*w1[4*j4+1] + xv.z*w1[4*j4+2] + xv.w*w1[4*j4+3];
      }
      const int sw = ((r >> 1) & 7) << 2;
      Hs[r*512 + (h0 ^ sw)] = 1.0f / (1.0f + __expf(-a0));
      Hs[r*512 + (h1 ^ sw)] = 1.0f / (1.0f + __expf(-a1));
    }
  }
  __syncthreads();

  // ---- G = H H^T : 2x2 register tiles, upper triangle of 14x14 tile grid ----
  if (tid < 105) {
    int rem = tid, ta = 0;
    while (rem >= 14 - ta) { rem -= 14 - ta; ++ta; }
    const int tc = ta + rem;
    const int a0 = 2*ta, c0 = 2*tc;
    const int sa = ta & 7, sc = tc & 7;
    const float4* H4 = reinterpret_cast<const float4*>(Hs);
    float s00=0.f, s01=0.f, s10=0.f, s11=0.f;
    for (int i = 0; i < 128; ++i) {
      const int h4 = (i + tid) & 127;          // per-lane phase rotation
      const float4 av0 = H4[(a0    )*128 + (h4 ^ sa)];
      const float4 av1 = H4[(a0 + 1)*128 + (h4 ^ sa)];
      const float4 cv0 = H4[(c0    )*128 + (h4 ^ sc)];
      const float4 cv1 = H4[(c0 + 1)*128 + (h4 ^ sc)];
      s00 += dot4f(av0, cv0);
      s01 += dot4f(av0, cv1);
      s10 += dot4f(av1, cv0);
      s11 += dot4f(av1, cv1);
    }
    Gc[(a0    )*32 + c0    ] = s00;
    Gc[(a0    )*32 + c0 + 1] = s01;
    Gc[(a0 + 1)*32 + c0    ] = s10;
    Gc[(a0 + 1)*32 + c0 + 1] = s11;
    // mirror (diagonal tiles overwrite with identical values)
    Gc[(c0    )*32 + a0    ] = s00;
    Gc[(c0 + 1)*32 + a0    ] = s01;
    Gc[(c0    )*32 + a0 + 1] = s10;
    Gc[(c0 + 1)*32 + a0 + 1] = s11;
  }
  __syncthreads();

  // ---- solve G Y = x : Gauss-Jordan on wave 0, lane j owns augmented col j ----
  if (tid < 64) {
    const int j = tid;
    float col[28];
#pragma unroll
    for (int r = 0; r < 28; ++r) {
      float v = 0.f;
      if (j < 28)       v = Gc[r*32 + j];            // left block: G
      else if (j < 56)  v = xsb[r*36 + (j - 28)];    // right block: x
      col[r] = v;
    }
#pragma unroll
    for (int k = 0; k < 28; ++k) {
      const float piv    = __shfl(col[k], k);        // A[k][k]
      const float pivinv = 1.0f / piv;
      col[k] *= pivinv;                              // scale pivot row
#pragma unroll
      for (int r = 0; r < 28; ++r) {
        if (r == k) continue;
        const float m = __shfl(col[r], k);           // A[r][k] (lane k)
        col[r] -= m * col[k];
      }
    }
    // write Y^T into xsb: Yt[c][a] = Y[a][c]  (xs no longer needed)
    if (j >= 28 && j < 56) {
      const int c = j - 28;
#pragma unroll
      for (int r = 0; r < 28; ++r) xsb[c*36 + r] = col[r];
    }
  }
  __syncthreads();

  // ---- X = G Y  (coalesced stores) ----
  {
    float* XO = Xout + (size_t)n * 784;
    for (int idx = tid; idx < 784; idx += THREADS) {
      const int r = idx / 28, c = idx - r*28;
      const float4* g4 = reinterpret_cast<const float4*>(&Gc[r*32]);
      const float4* y4 = reinterpret_cast<const float4*>(&xsb[c*36]);
      float acc = 0.f;
#pragma unroll
      for (int a4 = 0; a4 < 7; ++a4) acc += dot4f(g4[a4], y4[a4]);
      XO[idx] = acc;
    }
  }

  // ---- B = H^T Y : H-columns register-cached, Y rows broadcast float4 ----
  {
    float* BO = Bout + (size_t)n * (512*28);
    const int h0 = tid, h1 = tid + THREADS;
    float hc0[28], hc1[28];
#pragma unroll
    for (int a = 0; a < 28; ++a) {
      const int sw = ((a >> 1) & 7) << 2;
      hc0[a] = Hs[a*512 + (h0 ^ sw)];
      hc1[a] = Hs[a*512 + (h1 ^ sw)];
    }
#pragma unroll 4
    for (int c = 0; c < 28; ++c) {
      const float4* y4 = reinterpret_cast<const float4*>(&xsb[c*36]);
      float acc0 = 0.f, acc1 = 0.f;
#pragma unroll
      for (int a4 = 0; a4 < 7; ++a4) {
        const float4 yv = y4[a4];
        acc0 += hc0[4*a4]*yv.x + hc0[4*a4+1]*yv.y + hc0[4*a4+2]*yv.z + hc0[4*a4+3]*yv.w;
        acc1 += hc1[4*a4]*yv.x + hc1[4*a4+1]*yv.y + hc1[4*a4+2]*yv.z + hc1[4*a4+3]*yv.w;
      }
      BO[h0*28 + c] = acc0;
      BO[h1*28 + c] = acc1;
    }
  }
}

extern "C" void kernel_launch(void* const* d_in, const int* in_sizes, int n_in,
                              void* d_out, int out_size, void* d_ws, size_t ws_size,
                              hipStream_t stream) {
  const float* x = (const float*)d_in[0];
  const float* W = (const float*)d_in[1];
  const float* b = (const float*)d_in[2];
  const int N = in_sizes[0] / 784;              // 4096 samples
  float* Xout = (float*)d_out;                  // [N,1,28,28]
  float* Bout = Xout + (size_t)N * 784;         // [N,1,512,28]
  elm_kernel<<<N, THREADS, 0, stream>>>(x, W, b, Xout, Bout);
}

// Round 2
// 284.649 us; speedup vs baseline: 1.0863x; 1.0863x over previous
//
#include <hip/hip_runtime.h>

#define THREADS 256

__device__ __forceinline__ float dot4f(float4 a, float4 b) {
  return a.x*b.x + a.y*b.y + a.z*b.z + a.w*b.w;
}

// One block = one sample. x_i: [28][28], W: [512][28], b: [512]
// H = sigmoid(x W^T + b) : [28][512]   (thread t owns columns t, t+256)
// G = H H^T : [28][28];  Y = G^{-1} x  (Gauss-Jordan, wave 0)
// X = x exactly (H full row-rank => H pinv(H) = I)
// B = H^T Y : [512][28], staged in LDS (reusing Hs) then coalesced flush.
//
// Hs layout: granule-swizzled. Element (r,h) lives at float index
//   r*512 + (((h>>2) ^ (r&7))<<2) + (h&3)
__global__ __launch_bounds__(THREADS, 2) void elm_kernel(
    const float* __restrict__ x, const float* __restrict__ W,
    const float* __restrict__ bias, float* __restrict__ Xout,
    float* __restrict__ Bout)
{
  __shared__ float Hs[28*512];    // 57344 B ; later reused as B staging
  __shared__ float xsb[28*36];    // x (phase 1..solve), then Y^T[c][a] at c*36+a
  __shared__ float Gc[28*32];     // G[a][c] at a*32+c
  __shared__ float scratchD[14*4];// diagonal-tile half-1 partials

  const int tid = threadIdx.x;
  const int n   = blockIdx.x;
  const float* xi = x + (size_t)n * 784;

  // ---- load x into LDS + X output = copy of x (fire early) ----
  if (tid < 196) {
    const float4 v = reinterpret_cast<const float4*>(xi)[tid];
    reinterpret_cast<float4*>(Xout + (size_t)n * 784)[tid] = v;
    const int r = tid / 7, c4 = tid - r * 7;
    reinterpret_cast<float4*>(xsb)[r*9 + c4] = v;   // row stride 36 = 9 granules
  }
  __syncthreads();

  // ---- H = sigmoid(x W^T + b); keep own columns in regs + swizzled LDS store ----
  float hc0[28], hc1[28];
  {
    float w0[28], w1[28];
    const float4* W4 = reinterpret_cast<const float4*>(W);
#pragma unroll
    for (int j4 = 0; j4 < 7; ++j4) {
      const float4 v0 = W4[tid*7 + j4];
      const float4 v1 = W4[(tid+256)*7 + j4];
      w0[4*j4+0]=v0.x; w0[4*j4+1]=v0.y; w0[4*j4+2]=v0.z; w0[4*j4+3]=v0.w;
      w1[4*j4+0]=v1.x; w1[4*j4+1]=v1.y; w1[4*j4+2]=v1.z; w1[4*j4+3]=v1.w;
    }
    const float b0 = bias[tid], b1 = bias[tid+256];
    const int tg = tid >> 2, tl = tid & 3;
#pragma unroll 4
    for (int r = 0; r < 28; ++r) {
      const float4* xr4 = reinterpret_cast<const float4*>(&xsb[r*36]);
      float a0 = b0, a1 = b1;
#pragma unroll
      for (int j4 = 0; j4 < 7; ++j4) {
        const float4 xv = xr4[j4];
        a0 += xv.x*w0[4*j4] + xv.y*w0[4*j4+1] + xv.z*w0[4*j4+2] + xv.w*w0[4*j4+3];
        a1 += xv.x*w1[4*j4] + xv.y*w1[4*j4+1] + xv.z*w1[4*j4+2] + xv.w*w1[4*j4+3];
      }
      const float h0v = 1.0f / (1.0f + __expf(-a0));
      const float h1v = 1.0f / (1.0f + __expf(-a1));
      hc0[r] = h0v; hc1[r] = h1v;
      const int base = r*512 + (((tg) ^ (r&7)) << 2) + tl;
      Hs[base]       = h0v;       // column tid   (granule tg)
      Hs[base + 256] = h1v;       // column tid+256 (granule tg+64: (g+64)^s == (g^s)+64)
    }
  }
  __syncthreads();

  // ---- G partials: 105 upper-tri 2x2 tiles x 2 h-halves = 210 threads ----
  if (tid < 210) {
    const int half = (tid >= 105) ? 1 : 0;
    const int tile = tid - 105*half;
    int rem = tile, ta = 0;
    while (rem >= 14 - ta) { rem -= 14 - ta; ++ta; }
    const int tc = ta + rem;
    const int r0 = 2*ta, r1 = 2*ta+1, q0 = 2*tc, q1 = 2*tc+1;
    const int ba0 = r0*128, ba1 = r1*128, bc0 = q0*128, bc1 = q1*128;
    const int sa0 = r0&7,   sa1 = r1&7,   sc0 = q0&7,   sc1 = q1&7;
    const int hbase = half << 6;
    const float4* H4 = reinterpret_cast<const float4*>(Hs);
    float s00=0.f, s01=0.f, s10=0.f, s11=0.f;
    for (int i = 0; i < 64; ++i) {
      const int hg = ((i + tid) & 63) + hbase;     // per-lane phase rotation
      const float4 av0 = H4[ba0 + (hg ^ sa0)];
      const float4 av1 = H4[ba1 + (hg ^ sa1)];
      const float4 cv0 = H4[bc0 + (hg ^ sc0)];
      const float4 cv1 = H4[bc1 + (hg ^ sc1)];
      s00 += dot4f(av0, cv0);
      s01 += dot4f(av0, cv1);
      s10 += dot4f(av1, cv0);
      s11 += dot4f(av1, cv1);
    }
    if (half == 0) {
      Gc[r0*32 + q0] = s00; Gc[r0*32 + q1] = s01;
      Gc[r1*32 + q0] = s10; Gc[r1*32 + q1] = s11;
    } else if (ta != tc) {            // store transposed (lower region)
      Gc[q0*32 + r0] = s00; Gc[q1*32 + r0] = s01;
      Gc[q0*32 + r1] = s10; Gc[q1*32 + r1] = s11;
    } else {                          // diagonal tile: tiny scratch
      scratchD[ta*4+0] = s00; scratchD[ta*4+1] = s01;
      scratchD[ta*4+2] = s10; scratchD[ta*4+3] = s11;
    }
  }
  __syncthreads();

  // ---- G combine: 105 threads sum the two halves, mirror symmetric ----
  if (tid < 105) {
    int rem = tid, ta = 0;
    while (rem >= 14 - ta) { rem -= 14 - ta; ++ta; }
    const int tc = ta + rem;
    const int r0 = 2*ta, r1 = 2*ta+1, q0 = 2*tc, q1 = 2*tc+1;
    if (ta != tc) {
      const float u00 = Gc[r0*32+q0], u01 = Gc[r0*32+q1];
      const float u10 = Gc[r1*32+q0], u11 = Gc[r1*32+q1];
      const float l00 = Gc[q0*32+r0], l01 = Gc[q1*32+r0];
      const float l10 = Gc[q0*32+r1], l11 = Gc[q1*32+r1];
      const float t00 = u00+l00, t01 = u01+l01, t10 = u10+l10, t11 = u11+l11;
      Gc[r0*32+q0] = t00; Gc[r0*32+q1] = t01;
      Gc[r1*32+q0] = t10; Gc[r1*32+q1] = t11;
      Gc[q0*32+r0] = t00; Gc[q1*32+r0] = t01;
      Gc[q0*32+r1] = t10; Gc[q1*32+r1] = t11;
    } else {
      Gc[r0*32+q0] += scratchD[ta*4+0];
      Gc[r0*32+q1] += scratchD[ta*4+1];
      Gc[r1*32+q0] += scratchD[ta*4+2];
      Gc[r1*32+q1] += scratchD[ta*4+3];
    }
  }
  __syncthreads();

  // ---- solve G Y = x : Gauss-Jordan on wave 0, lane j owns augmented col j ----
  if (tid < 64) {
    const int j = tid;
    float col[28];
#pragma unroll
    for (int r = 0; r < 28; ++r) {
      float v = 0.f;
      if (j < 28)       v = Gc[r*32 + j];
      else if (j < 56)  v = xsb[r*36 + (j - 28)];
      col[r] = v;
    }
#pragma unroll
    for (int k = 0; k < 28; ++k) {
      const float piv    = __shfl(col[k], k);
      const float pivinv = 1.0f / piv;
      col[k] *= pivinv;
#pragma unroll
      for (int r = 0; r < 28; ++r) {
        if (r == k) continue;
        const float m = __shfl(col[r], k);
        col[r] -= m * col[k];
      }
    }
    if (j >= 28 && j < 56) {          // write Y^T: Yt[c][a] = Y[a][c]
      const int c = j - 28;
#pragma unroll
      for (int r = 0; r < 28; ++r) xsb[c*36 + r] = col[r];
    }
  }
  __syncthreads();   // after this: Hs no longer read as H -> safe to reuse as Bs

  // ---- B = H^T Y from register H-columns; stage rows in LDS (reuse Hs) ----
  {
    float* Bs = Hs;
#pragma unroll
    for (int c4 = 0; c4 < 7; ++c4) {
      float a0v[4], a1v[4];
#pragma unroll
      for (int cc = 0; cc < 4; ++cc) {
        const int c = c4*4 + cc;
        const float4* y4 = reinterpret_cast<const float4*>(&xsb[c*36]);
        float acc0 = 0.f, acc1 = 0.f;
#pragma unroll
        for (int a4 = 0; a4 < 7; ++a4) {
          const float4 yv = y4[a4];
          acc0 += hc0[4*a4]*yv.x + hc0[4*a4+1]*yv.y + hc0[4*a4+2]*yv.z + hc0[4*a4+3]*yv.w;
          acc1 += hc1[4*a4]*yv.x + hc1[4*a4+1]*yv.y + hc1[4*a4+2]*yv.z + hc1[4*a4+3]*yv.w;
        }
        a0v[cc] = acc0; a1v[cc] = acc1;
      }
      float4 A0, A1;
      A0.x=a0v[0]; A0.y=a0v[1]; A0.z=a0v[2]; A0.w=a0v[3];
      A1.x=a1v[0]; A1.y=a1v[1]; A1.z=a1v[2]; A1.w=a1v[3];
      *reinterpret_cast<float4*>(&Bs[tid*28       + 4*c4]) = A0;  // row tid
      *reinterpret_cast<float4*>(&Bs[tid*28 + 7168 + 4*c4]) = A1; // row tid+256
    }
  }
  __syncthreads();

  // ---- coalesced flush of B: 3584 float4 ----
  {
    const float4* Bs4 = reinterpret_cast<const float4*>(Hs);
    float4* BO4 = reinterpret_cast<float4*>(Bout + (size_t)n * 14336);
#pragma unroll
    for (int k = 0; k < 14; ++k) {
      BO4[tid + k*256] = Bs4[tid + k*256];
    }
  }
}

extern "C" void kernel_launch(void* const* d_in, const int* in_sizes, int n_in,
                              void* d_out, int out_size, void* d_ws, size_t ws_size,
                              hipStream_t stream) {
  const float* x = (const float*)d_in[0];
  const float* W = (const float*)d_in[1];
  const float* b = (const float*)d_in[2];
  const int N = in_sizes[0] / 784;              // 4096 samples
  float* Xout = (float*)d_out;                  // [N,1,28,28]
  float* Bout = Xout + (size_t)N * 784;         // [N,1,512,28]
  elm_kernel<<<N, THREADS, 0, stream>>>(x, W, b, Xout, Bout);
}